// Round 6
// baseline (1411.757 us; speedup 1.0000x reference)
//
#include <hip/hip_runtime.h>
#include <cstdint>

#define UNITS 128
#define GATES 512            // 4*UNITS
#define IN_DIM 128
#define BATCH 64
#define SEQ 2048
#define ROWS (BATCH * SEQ)   // 131072

typedef _Float16 f16;
typedef _Float16 f16x2 __attribute__((ext_vector_type(2)));
typedef _Float16 f16x8 __attribute__((ext_vector_type(8)));
typedef float    f32x4 __attribute__((ext_vector_type(4)));

static __device__ __forceinline__ float sigmoid_f(float x) {
    float e = __builtin_amdgcn_exp2f(-1.44269504f * x);
    return __builtin_amdgcn_rcpf(1.0f + e);
}
static __device__ __forceinline__ float tanh_f(float x) {
    float e = __builtin_amdgcn_exp2f(2.8853900817779268f * x);
    return 1.0f - 2.0f * __builtin_amdgcn_rcpf(1.0f + e);
}

// Workgroup barrier ordering LDS only (no vmcnt(0) drain of stores/prefetch).
static __device__ __forceinline__ void lds_barrier() {
    __asm__ volatile("s_waitcnt lgkmcnt(0)\n\ts_barrier" ::: "memory");
}

// ---------------------------------------------------------------------------
// Kernel 1: WxT[n][k] = (f16)Wx[k][n]
// ---------------------------------------------------------------------------
__global__ void wxt_kernel(const float* __restrict__ W,
                           f16* __restrict__ WxT) {
    int idx = blockIdx.x * 256 + threadIdx.x;     // over Wx (128x512)
    int k = idx >> 9, n = idx & 511;
    WxT[n * IN_DIM + k] = (f16)W[idx];
}

// ---------------------------------------------------------------------------
// Kernel 2: xp = data @ Wx + b  -> SWIZZLED f16 layout co-designed with the
// scan:  xp_swz[row][w][l16][r]  (flat: row*512 + w*128 + l16*8 + r), where
// col = 128*(r>>1) + 32*w + 16*(r&1) + l16.  The scan's lane l16 of wave w
// then reads its 8 per-step gate pre-activations as ONE b128 load, and this
// kernel stores b128 (round 5: 256 scalar f16 stores/thread, ~168 us w/ wxt).
// ---------------------------------------------------------------------------
__global__ __launch_bounds__(256) void xp_gemm(
        const float* __restrict__ A,      // data f32, ROWS x 128
        const f16*  __restrict__ WxT,     // 512 x 128 f16
        const float* __restrict__ bias,   // 512 f32
        f16* __restrict__ xp) {           // ROWS x 512 f16 (swizzled)
    const int wave = threadIdx.x >> 6;
    const int lane = threadIdx.x & 63;
    const int m16  = lane & 15;
    const int q    = lane >> 4;
    const int rowBase = blockIdx.x * 128 + wave * 32;

    f16x8 a[2][4];
    #pragma unroll
    for (int mc = 0; mc < 2; ++mc)
        #pragma unroll
        for (int ks = 0; ks < 4; ++ks) {
            const float* p = A + (size_t)(rowBase + mc * 16 + m16) * IN_DIM
                               + ks * 32 + q * 8;
            float4 lo = *(const float4*)p;
            float4 hi = *(const float4*)(p + 4);
            f16x8 v;
            v[0] = (f16)lo.x; v[1] = (f16)lo.y; v[2] = (f16)lo.z; v[3] = (f16)lo.w;
            v[4] = (f16)hi.x; v[5] = (f16)hi.y; v[6] = (f16)hi.z; v[7] = (f16)hi.w;
            a[mc][ks] = v;
        }

    #pragma unroll
    for (int w = 0; w < 4; ++w) {
        f32x4 acc[2][8];
        float bv[8];
        #pragma unroll
        for (int r = 0; r < 8; ++r) {
            const int nt = 8 * (r >> 1) + 2 * w + (r & 1);   // bijective over 32
            f16x8 bfr[4];
            #pragma unroll
            for (int ks = 0; ks < 4; ++ks)
                bfr[ks] = *(const f16x8*)(WxT + (nt * 16 + m16) * IN_DIM
                                              + ks * 32 + q * 8);
            acc[0][r] = f32x4{0.f, 0.f, 0.f, 0.f};
            acc[1][r] = f32x4{0.f, 0.f, 0.f, 0.f};
            #pragma unroll
            for (int ks = 0; ks < 4; ++ks) {
                acc[0][r] = __builtin_amdgcn_mfma_f32_16x16x32_f16(a[0][ks], bfr[ks], acc[0][r], 0, 0, 0);
                acc[1][r] = __builtin_amdgcn_mfma_f32_16x16x32_f16(a[1][ks], bfr[ks], acc[1][r], 0, 0, 0);
            }
            bv[r] = bias[nt * 16 + m16];
        }
        // Pack 8 f16 per (row, w) and store as one b128.
        #pragma unroll
        for (int mc = 0; mc < 2; ++mc)
            #pragma unroll
            for (int rr = 0; rr < 4; ++rr) {
                const int row = rowBase + mc * 16 + q * 4 + rr;  // D row=q*4+rr
                f16x8 v;
                #pragma unroll
                for (int r = 0; r < 8; ++r)
                    v[r] = (f16)(acc[mc][r][rr] + bv[r]);
                *(f16x8*)(xp + (size_t)row * 512 + w * 128 + m16 * 8) = v;
            }
    }
}

// ---------------------------------------------------------------------------
// Kernel 3: MFMA scan. 64 WGs (one sample each), 256 threads (4 waves).
//
// Per step: gates z = h @ Wh as mfma_f32_16x16x32_f16 with M=1 (rows 1..15
// garbage, never read). Wave w owns cells [32w,32w+32): 8 n-tiles
// (col = 128*gate + 32w + 16*hh), B-frags register-resident (128 VGPRs).
// A-frag: every lane reads h[q*8..q*8+7] -> 4 ds_read_b128, quad-broadcast.
// z lands in lanes 0..15 reg0 of the 8 accs -> cell update is lane-local
// (cells 32w+l and 32w+16+l), no shuffles. One lds_barrier per step.
// Round-5 post-mortem: fdot2 issues at ~4cy/wave64 -> 512cy/step floor on
// the VALU; MFMA moves the matvec to the matrix pipe (~154 cy).
// ---------------------------------------------------------------------------
__global__ __launch_bounds__(256, 1) void lstm_scan_mfma(
        const float* __restrict__ W,      // 256 x 512 f32
        const f16* __restrict__ xp,       // swizzled, see xp_gemm
        float* __restrict__ out) {        // ROWS x 128 f32
    __shared__ __align__(16) f16 h_lds[2][UNITS];

    const int tid = threadIdx.x;
    const int b   = blockIdx.x;
    const int w   = tid >> 6;
    const int l   = tid & 63;
    const int m16 = l & 15;
    const int q   = l >> 4;

    // B frags: whb[r][kt], lane l holds B[k=kt*32+q*8+j][n=colb] (same
    // pattern as the validated xp_gemm B load). Fully unrolled.
    f16x8 whb[8][4];
    #pragma unroll
    for (int r = 0; r < 8; ++r) {
        const int colb = 128 * (r >> 1) + 32 * w + 16 * (r & 1) + m16;
        #pragma unroll
        for (int kt = 0; kt < 4; ++kt) {
            f16x8 v;
            #pragma unroll
            for (int j = 0; j < 8; ++j)
                v[j] = (f16)W[(size_t)(IN_DIM + kt * 32 + q * 8 + j) * GATES + colb];
            whb[r][kt] = v;
        }
    }

    float cs0 = 1.0f, cs1 = 1.0f;                  // c0 = ones (2 cells/lane)
    if (tid < UNITS) h_lds[0][tid] = (f16)0.f;     // h0 = zeros

    const f16* xpb = xp + (size_t)b * SEQ * 512 + w * 128 + m16 * 8;
    // xp prefetch pipeline, distance 2. All lanes load (quads dedup).
    f16x8 xA = *(const f16x8*)(xpb);
    f16x8 xB = *(const f16x8*)(xpb + 512);
    __syncthreads();

    for (int t = 0; t < SEQ; ++t) {
        const int cur = t & 1, nxt = cur ^ 1;
        f16x8 xcur = xA;
        xA = xB;
        {
            int t2 = (t + 2 < SEQ) ? (t + 2) : (SEQ - 1);
            xB = *(const f16x8*)(xpb + (size_t)t2 * 512);
        }

        // A-frags: h[kt*32 + q*8 .. +7] — 4 x b128, 4 distinct addrs/wave.
        const char* hbase = (const char*)(&h_lds[cur][0]);
        f16x8 af[4];
        #pragma unroll
        for (int kt = 0; kt < 4; ++kt)
            af[kt] = *(const f16x8*)(hbase + kt * 64 + q * 16);

        f32x4 acc[8];
        #pragma unroll
        for (int r = 0; r < 8; ++r) {
            f32x4 z = f32x4{0.f, 0.f, 0.f, 0.f};
            #pragma unroll
            for (int kt = 0; kt < 4; ++kt)
                z = __builtin_amdgcn_mfma_f32_16x16x32_f16(af[kt], whb[r][kt], z, 0, 0, 0);
            acc[r] = z;
        }

        if (q == 0) {   // lanes 0..15 hold row 0 (reg 0) of every acc
            float zi0 = acc[0][0] + (float)xcur[0];
            float zi1 = acc[1][0] + (float)xcur[1];
            float zf0 = acc[2][0] + (float)xcur[2];
            float zf1 = acc[3][0] + (float)xcur[3];
            float zo0 = acc[4][0] + (float)xcur[4];
            float zo1 = acc[5][0] + (float)xcur[5];
            float zg0 = acc[6][0] + (float)xcur[6];
            float zg1 = acc[7][0] + (float)xcur[7];
            cs0 = sigmoid_f(zf0) * cs0 + sigmoid_f(zi0) * tanh_f(zg0);
            cs1 = sigmoid_f(zf1) * cs1 + sigmoid_f(zi1) * tanh_f(zg1);
            float h0 = sigmoid_f(zo0) * tanh_f(cs0);
            float h1 = sigmoid_f(zo1) * tanh_f(cs1);
            h_lds[nxt][32 * w + m16]      = (f16)h0;
            h_lds[nxt][32 * w + 16 + m16] = (f16)h1;
            float* op = out + ((size_t)b * SEQ + t) * UNITS + 32 * w;
            op[m16]      = h0;
            op[16 + m16] = h1;
        }
        lds_barrier();
    }
}

// ---------------------------------------------------------------------------
// Fallback (ws too small): fused fdot2 scan, Wx in registers. Known-good
// structure from round 5 (FUSED path only).
// ---------------------------------------------------------------------------
__global__ __launch_bounds__(256, 1) void lstm_scan_fused(
        const float* __restrict__ W,
        const float* __restrict__ bias,
        const float* __restrict__ data,
        float* __restrict__ out) {
    __shared__ __align__(16) f16 h_lds[2][UNITS];
    __shared__ __align__(16) f16 x_lds[2][UNITS];

    const int tid  = threadIdx.x;
    const int b    = blockIdx.x;
    const int wave = tid >> 6;
    const int lane = tid & 63;
    const int half = lane >> 5;
    const int cell = wave * 32 + (lane & 31);
    const int c0   = cell + half * 256;
    const int c1   = c0 + 128;

    f16x2 wh0[64], wh1[64], wxa[64], wxb[64];
    #pragma unroll
    for (int k = 0; k < 64; ++k) {
        wh0[k] = f16x2{(f16)W[(size_t)(IN_DIM + 2 * k) * GATES + c0],
                       (f16)W[(size_t)(IN_DIM + 2 * k + 1) * GATES + c0]};
        wh1[k] = f16x2{(f16)W[(size_t)(IN_DIM + 2 * k) * GATES + c1],
                       (f16)W[(size_t)(IN_DIM + 2 * k + 1) * GATES + c1]};
        wxa[k] = f16x2{(f16)W[(size_t)(2 * k) * GATES + c0],
                       (f16)W[(size_t)(2 * k + 1) * GATES + c0]};
        wxb[k] = f16x2{(f16)W[(size_t)(2 * k) * GATES + c1],
                       (f16)W[(size_t)(2 * k + 1) * GATES + c1]};
    }
    float bb0 = bias[c0], bb1 = bias[c1];

    float c = 1.0f;
    if (tid < UNITS) {
        h_lds[0][tid] = (f16)0.f;
        x_lds[0][tid] = (f16)data[(size_t)b * SEQ * IN_DIM + tid];
    }
    __syncthreads();

    for (int t = 0; t < SEQ; ++t) {
        const int cur = t & 1, nxt = cur ^ 1;
        float a00 = bb0, a01 = 0.f, a10 = bb1, a11 = 0.f;

        const uint4* xsrc = (const uint4*)(&x_lds[cur][0]);
        const uint4* hsrc = (const uint4*)(&h_lds[cur][0]);
        uint4 xb[16], hb[16];
        #pragma unroll
        for (int i = 0; i < 16; ++i) { xb[i] = xsrc[i]; hb[i] = hsrc[i]; }
        #pragma unroll
        for (int i = 0; i < 16; ++i) {
            f16x2 x0 = __builtin_bit_cast(f16x2, xb[i].x);
            f16x2 x1 = __builtin_bit_cast(f16x2, xb[i].y);
            f16x2 x2 = __builtin_bit_cast(f16x2, xb[i].z);
            f16x2 x3 = __builtin_bit_cast(f16x2, xb[i].w);
            f16x2 h0 = __builtin_bit_cast(f16x2, hb[i].x);
            f16x2 h1 = __builtin_bit_cast(f16x2, hb[i].y);
            f16x2 h2 = __builtin_bit_cast(f16x2, hb[i].z);
            f16x2 h3 = __builtin_bit_cast(f16x2, hb[i].w);
            const int k = 4 * i;
            if (i < 8) {
                a00 = __builtin_amdgcn_fdot2(x0, wxa[k],     a00, false);
                a10 = __builtin_amdgcn_fdot2(x0, wxb[k],     a10, false);
                a00 = __builtin_amdgcn_fdot2(x1, wxa[k + 1], a00, false);
                a10 = __builtin_amdgcn_fdot2(x1, wxb[k + 1], a10, false);
                a00 = __builtin_amdgcn_fdot2(x2, wxa[k + 2], a00, false);
                a10 = __builtin_amdgcn_fdot2(x2, wxb[k + 2], a10, false);
                a00 = __builtin_amdgcn_fdot2(x3, wxa[k + 3], a00, false);
                a10 = __builtin_amdgcn_fdot2(x3, wxb[k + 3], a10, false);
                a00 = __builtin_amdgcn_fdot2(h0, wh0[k],     a00, false);
                a10 = __builtin_amdgcn_fdot2(h0, wh1[k],     a10, false);
                a00 = __builtin_amdgcn_fdot2(h1, wh0[k + 1], a00, false);
                a10 = __builtin_amdgcn_fdot2(h1, wh1[k + 1], a10, false);
                a00 = __builtin_amdgcn_fdot2(h2, wh0[k + 2], a00, false);
                a10 = __builtin_amdgcn_fdot2(h2, wh1[k + 2], a10, false);
                a00 = __builtin_amdgcn_fdot2(h3, wh0[k + 3], a00, false);
                a10 = __builtin_amdgcn_fdot2(h3, wh1[k + 3], a10, false);
            } else {
                a01 = __builtin_amdgcn_fdot2(x0, wxa[k],     a01, false);
                a11 = __builtin_amdgcn_fdot2(x0, wxb[k],     a11, false);
                a01 = __builtin_amdgcn_fdot2(x1, wxa[k + 1], a01, false);
                a11 = __builtin_amdgcn_fdot2(x1, wxb[k + 1], a11, false);
                a01 = __builtin_amdgcn_fdot2(x2, wxa[k + 2], a01, false);
                a11 = __builtin_amdgcn_fdot2(x2, wxb[k + 2], a11, false);
                a01 = __builtin_amdgcn_fdot2(x3, wxa[k + 3], a01, false);
                a11 = __builtin_amdgcn_fdot2(x3, wxb[k + 3], a11, false);
                a01 = __builtin_amdgcn_fdot2(h0, wh0[k],     a01, false);
                a11 = __builtin_amdgcn_fdot2(h0, wh1[k],     a11, false);
                a01 = __builtin_amdgcn_fdot2(h1, wh0[k + 1], a01, false);
                a11 = __builtin_amdgcn_fdot2(h1, wh1[k + 1], a11, false);
                a01 = __builtin_amdgcn_fdot2(h2, wh0[k + 2], a01, false);
                a11 = __builtin_amdgcn_fdot2(h2, wh1[k + 2], a11, false);
                a01 = __builtin_amdgcn_fdot2(h3, wh0[k + 3], a01, false);
                a11 = __builtin_amdgcn_fdot2(h3, wh1[k + 3], a11, false);
            }
        }
        float z0 = a00 + a01, z1 = a10 + a11;
        float s0 = sigmoid_f(z0);
        float s1 = (half == 0) ? sigmoid_f(z1) : tanh_f(z1);
        float p0 = __shfl_xor(s0, 32, 64);
        float p1 = __shfl_xor(s1, 32, 64);
        if (half == 0) {
            c = s1 * c + s0 * p1;
            float h = p0 * tanh_f(c);
            h_lds[nxt][cell] = (f16)h;
            out[((size_t)b * SEQ + t) * UNITS + cell] = h;
        }
        if (tid < UNITS) {
            int t1 = (t + 1 < SEQ) ? (t + 1) : t;
            x_lds[nxt][tid] = (f16)data[(size_t)b * SEQ * IN_DIM
                                        + (size_t)t1 * IN_DIM + tid];
        }
        lds_barrier();
    }
}

// ---------------------------------------------------------------------------
extern "C" void kernel_launch(void* const* d_in, const int* in_sizes, int n_in,
                              void* d_out, int out_size, void* d_ws, size_t ws_size,
                              hipStream_t stream) {
    const float* data = (const float*)d_in[0];   // f32 (64,2048,128)
    const float* W    = (const float*)d_in[1];   // f32 (256,512)
    const float* bias = (const float*)d_in[2];   // f32 (512,)
    float* out = (float*)d_out;                  // f32 (64,2048,128)

    const size_t wxt_bytes = (size_t)GATES * IN_DIM * sizeof(f16);  // 128 KiB
    const size_t xp_bytes  = (size_t)ROWS * GATES * sizeof(f16);    // 128 MiB
    if (ws_size >= wxt_bytes + xp_bytes) {
        f16* WxT = (f16*)d_ws;
        f16* xp  = (f16*)((char*)d_ws + wxt_bytes);
        hipLaunchKernelGGL(wxt_kernel, dim3(256), dim3(256), 0, stream, W, WxT);
        hipLaunchKernelGGL(xp_gemm, dim3(ROWS / 128), dim3(256), 0, stream,
                           data, WxT, bias, xp);
        hipLaunchKernelGGL(lstm_scan_mfma, dim3(BATCH), dim3(256), 0, stream,
                           W, xp, out);
    } else {
        hipLaunchKernelGGL(lstm_scan_fused, dim3(BATCH), dim3(256), 0, stream,
                           W, bias, data, out);
    }
}